// Round 1
// baseline (370.151 us; speedup 1.0000x reference)
//
#include <hip/hip_runtime.h>
#include <hip/hip_bf16.h>
#include <stdint.h>
#include <math.h>

using u16    = unsigned short;
using short8 = __attribute__((ext_vector_type(8))) short;
using f32x4  = __attribute__((ext_vector_type(4))) float;

#define DEVI __device__ __forceinline__

static constexpr int S  = 2048;
static constexpr int D  = 512;
static constexpr int DH = 64;
static constexpr float SCALE = 0.04419417382415922f; // 1/sqrt(512)

DEVI u16 f2bf(float f){
  uint32_t u = __float_as_uint(f);
  u = u + 0x7FFFu + ((u >> 16) & 1u);   // RNE
  return (u16)(u >> 16);
}

// ---------------- fp32 -> bf16 convert ----------------
__global__ void k_cvt_bf16(const float* __restrict__ in, u16* __restrict__ out, int n4){
  int i = blockIdx.x * blockDim.x + threadIdx.x;
  if (i >= n4) return;
  float4 v = reinterpret_cast<const float4*>(in)[i];
  uint2 o;
  o.x = (uint32_t)f2bf(v.x) | ((uint32_t)f2bf(v.y) << 16);
  o.y = (uint32_t)f2bf(v.z) | ((uint32_t)f2bf(v.w) << 16);
  reinterpret_cast<uint2*>(out)[i] = o;
}

// ---------------- GEMM: C[m][n] = sum_k A[m][k]*W[n][k] + bias[n] ----------------
// MODE 0: out bf16 at ((b*8+h)*2048+s)*64+d          (m=(b,s), n=(h,d))
// MODE 2: out bf16 transposed ((b*8+h)*64+d)*2048+s
// MODE 3: A is head-interleaved bf16 ((b*8+h)*2048+s)*64+d with k=(h,d); out fp32 row-major
template<int MODE>
__global__ __launch_bounds__(256)
void k_gemm_bt(const u16* __restrict__ A, const u16* __restrict__ W,
               const float* __restrict__ bias, void* __restrict__ outp)
{
  __shared__ u16 As[128*64];
  __shared__ u16 Bs[128*64];
  const int tid = threadIdx.x;
  const int w = tid >> 6, l = tid & 63;
  const int m0 = blockIdx.x * 128, n0 = blockIdx.y * 128;

  f32x4 acc[2][8];
  #pragma unroll
  for (int i = 0; i < 2; i++)
    #pragma unroll
    for (int j = 0; j < 8; j++) acc[i][j] = (f32x4){0.f,0.f,0.f,0.f};

  for (int kt = 0; kt < D; kt += 64){
    __syncthreads();
    #pragma unroll
    for (int j = 0; j < 4; j++){
      int idx = j*256 + tid;
      int row = idx >> 3, c = idx & 7;
      int k = kt + c*8;
      long ga;
      if constexpr (MODE == 3){
        int m = m0 + row;
        ga = ((long)(((m >> 11)*8 + (k >> 6))*2048 + (m & 2047)))*64 + (k & 63);
      } else {
        ga = (long)(m0 + row)*D + k;
      }
      *reinterpret_cast<short8*>(&As[(row*8 + (c ^ (row & 7)))*8]) =
          *reinterpret_cast<const short8*>(&A[ga]);
      *reinterpret_cast<short8*>(&Bs[(row*8 + (c ^ (row & 7)))*8]) =
          *reinterpret_cast<const short8*>(&W[(long)(n0 + row)*D + k]);
    }
    __syncthreads();
    #pragma unroll
    for (int ks = 0; ks < 2; ks++){
      short8 af[2];
      #pragma unroll
      for (int mf = 0; mf < 2; mf++){
        int row = w*32 + mf*16 + (l & 15);
        int cw = (ks*4 + (l >> 4)) ^ (row & 7);
        af[mf] = *reinterpret_cast<const short8*>(&As[(row*8 + cw)*8]);
      }
      #pragma unroll
      for (int nf = 0; nf < 8; nf++){
        int row = nf*16 + (l & 15);
        int cw = (ks*4 + (l >> 4)) ^ (row & 7);
        short8 bf = *reinterpret_cast<const short8*>(&Bs[(row*8 + cw)*8]);
        #pragma unroll
        for (int mf = 0; mf < 2; mf++)
          acc[mf][nf] = __builtin_amdgcn_mfma_f32_16x16x32_bf16(af[mf], bf, acc[mf][nf], 0, 0, 0);
      }
    }
  }
  // epilogue
  #pragma unroll
  for (int mf = 0; mf < 2; mf++){
    #pragma unroll
    for (int nf = 0; nf < 8; nf++){
      int n = n0 + nf*16 + (l & 15);
      float bi = bias[n];
      if constexpr (MODE == 2){
        int mb = m0 + w*32 + mf*16 + (l >> 4)*4;
        int b_ = mb >> 11, s_ = mb & 2047;
        int h_ = n >> 6, d_ = n & 63;
        uint2 o;
        float v0 = acc[mf][nf][0] + bi, v1 = acc[mf][nf][1] + bi;
        float v2 = acc[mf][nf][2] + bi, v3 = acc[mf][nf][3] + bi;
        o.x = (uint32_t)f2bf(v0) | ((uint32_t)f2bf(v1) << 16);
        o.y = (uint32_t)f2bf(v2) | ((uint32_t)f2bf(v3) << 16);
        *reinterpret_cast<uint2*>(&((u16*)outp)[((long)((b_*8 + h_)*64 + d_))*2048 + s_]) = o;
      } else {
        #pragma unroll
        for (int r = 0; r < 4; r++){
          int m = m0 + w*32 + mf*16 + (l >> 4)*4 + r;
          float v = acc[mf][nf][r] + bi;
          if constexpr (MODE == 3){
            ((float*)outp)[(long)m*D + n] = v;
          } else {
            int b_ = m >> 11, s_ = m & 2047;
            int h_ = n >> 6, d_ = n & 63;
            ((u16*)outp)[((long)((b_*8 + h_)*2048 + s_))*64 + d_] = f2bf(v);
          }
        }
      }
    }
  }
}

// ---------------- attention pass 1: row max + sumexp ----------------
__global__ __launch_bounds__(256)
void k_attn_pass1(const u16* __restrict__ Qp, const u16* __restrict__ Kp,
                  float* __restrict__ mbuf, float* __restrict__ lbuf)
{
  __shared__ u16 Ks[128*64];
  const int tid = threadIdx.x, w = tid >> 6, l = tid & 63;
  const int qt = blockIdx.x, bh = blockIdx.y;
  const u16* Qb = Qp + (long)bh * S * DH;
  const u16* Kb = Kp + (long)bh * S * DH;

  short8 qf[2][2];
  #pragma unroll
  for (int mf = 0; mf < 2; mf++)
    #pragma unroll
    for (int ks = 0; ks < 2; ks++){
      int row = qt*128 + w*32 + mf*16 + (l & 15);
      qf[mf][ks] = *reinterpret_cast<const short8*>(&Qb[(long)row*DH + ks*32 + (l >> 4)*8]);
    }

  float m_run[2][4], l_run[2][4];
  #pragma unroll
  for (int mf = 0; mf < 2; mf++)
    #pragma unroll
    for (int r = 0; r < 4; r++){ m_run[mf][r] = -INFINITY; l_run[mf][r] = 0.f; }

  for (int kt = 0; kt < 16; kt++){
    __syncthreads();
    #pragma unroll
    for (int j = 0; j < 4; j++){
      int idx = j*256 + tid;
      int row = idx >> 3, c = idx & 7;
      *reinterpret_cast<short8*>(&Ks[(row*8 + (c ^ (row & 7)))*8]) =
          *reinterpret_cast<const short8*>(&Kb[(long)(kt*128 + row)*DH + c*8]);
    }
    __syncthreads();

    f32x4 sacc[2][8];
    #pragma unroll
    for (int i = 0; i < 2; i++)
      #pragma unroll
      for (int j = 0; j < 8; j++) sacc[i][j] = (f32x4){0.f,0.f,0.f,0.f};

    #pragma unroll
    for (int ks = 0; ks < 2; ks++)
      #pragma unroll
      for (int nf = 0; nf < 8; nf++){
        int row = nf*16 + (l & 15);
        int cw = (ks*4 + (l >> 4)) ^ (row & 7);
        short8 bf = *reinterpret_cast<const short8*>(&Ks[(row*8 + cw)*8]);
        #pragma unroll
        for (int mf = 0; mf < 2; mf++)
          sacc[mf][nf] = __builtin_amdgcn_mfma_f32_16x16x32_bf16(qf[mf][ks], bf, sacc[mf][nf], 0, 0, 0);
      }

    #pragma unroll
    for (int mf = 0; mf < 2; mf++){
      #pragma unroll
      for (int r = 0; r < 4; r++){
        float tm = -INFINITY;
        #pragma unroll
        for (int nf = 0; nf < 8; nf++){
          float sv = sacc[mf][nf][r] * SCALE;
          sacc[mf][nf][r] = sv;
          tm = fmaxf(tm, sv);
        }
        #pragma unroll
        for (int msk = 1; msk < 16; msk <<= 1) tm = fmaxf(tm, __shfl_xor(tm, msk, 64));
        float mn = fmaxf(m_run[mf][r], tm);
        float ts = 0.f;
        #pragma unroll
        for (int nf = 0; nf < 8; nf++) ts += __expf(sacc[mf][nf][r] - mn);
        #pragma unroll
        for (int msk = 1; msk < 16; msk <<= 1) ts += __shfl_xor(ts, msk, 64);
        l_run[mf][r] = l_run[mf][r] * __expf(m_run[mf][r] - mn) + ts;
        m_run[mf][r] = mn;
      }
    }
  }
  if ((l & 15) == 0){
    #pragma unroll
    for (int mf = 0; mf < 2; mf++)
      #pragma unroll
      for (int r = 0; r < 4; r++){
        int row = qt*128 + w*32 + mf*16 + (l >> 4)*4 + r;
        mbuf[bh*S + row] = m_run[mf][r];
        lbuf[bh*S + row] = l_run[mf][r];
      }
  }
}

// ---------------- attention pass 2: O = sum sigmoid(exp(s-m)/l) * V ----------------
__global__ __launch_bounds__(256)
void k_attn_pass2(const u16* __restrict__ Qp, const u16* __restrict__ Kp,
                  const u16* __restrict__ Vt, const float* __restrict__ mbuf,
                  const float* __restrict__ lbuf, u16* __restrict__ AO)
{
  __shared__ u16 Ks[128*64];
  __shared__ u16 Vs[64*128];
  __shared__ u16 Ps[4*32*128];   // per-wave P tile
  const int tid = threadIdx.x, w = tid >> 6, l = tid & 63;
  const int qt = blockIdx.x, bh = blockIdx.y;
  const u16* Qb = Qp + (long)bh * S * DH;
  const u16* Kb = Kp + (long)bh * S * DH;
  const u16* Vb = Vt + (long)bh * DH * S;

  short8 qf[2][2];
  #pragma unroll
  for (int mf = 0; mf < 2; mf++)
    #pragma unroll
    for (int ks = 0; ks < 2; ks++){
      int row = qt*128 + w*32 + mf*16 + (l & 15);
      qf[mf][ks] = *reinterpret_cast<const short8*>(&Qb[(long)row*DH + ks*32 + (l >> 4)*8]);
    }
  float mrow[2][4], linv[2][4];
  #pragma unroll
  for (int mf = 0; mf < 2; mf++)
    #pragma unroll
    for (int r = 0; r < 4; r++){
      int row = qt*128 + w*32 + mf*16 + (l >> 4)*4 + r;
      mrow[mf][r] = mbuf[bh*S + row];
      linv[mf][r] = 1.f / lbuf[bh*S + row];
    }
  f32x4 oacc[2][4];
  #pragma unroll
  for (int i = 0; i < 2; i++)
    #pragma unroll
    for (int j = 0; j < 4; j++) oacc[i][j] = (f32x4){0.f,0.f,0.f,0.f};

  for (int kt = 0; kt < 16; kt++){
    __syncthreads();
    #pragma unroll
    for (int j = 0; j < 4; j++){
      int idx = j*256 + tid;
      int row = idx >> 3, c = idx & 7;
      *reinterpret_cast<short8*>(&Ks[(row*8 + (c ^ (row & 7)))*8]) =
          *reinterpret_cast<const short8*>(&Kb[(long)(kt*128 + row)*DH + c*8]);
    }
    #pragma unroll
    for (int j = 0; j < 4; j++){
      int idx = j*256 + tid;
      int row = idx >> 4, c = idx & 15;
      *reinterpret_cast<short8*>(&Vs[(row*16 + (c ^ (row & 15)))*8]) =
          *reinterpret_cast<const short8*>(&Vb[(long)row*S + kt*128 + c*8]);
    }
    __syncthreads();

    f32x4 sacc[2][8];
    #pragma unroll
    for (int i = 0; i < 2; i++)
      #pragma unroll
      for (int j = 0; j < 8; j++) sacc[i][j] = (f32x4){0.f,0.f,0.f,0.f};

    #pragma unroll
    for (int ks = 0; ks < 2; ks++)
      #pragma unroll
      for (int nf = 0; nf < 8; nf++){
        int row = nf*16 + (l & 15);
        int cw = (ks*4 + (l >> 4)) ^ (row & 7);
        short8 bf = *reinterpret_cast<const short8*>(&Ks[(row*8 + cw)*8]);
        #pragma unroll
        for (int mf = 0; mf < 2; mf++)
          sacc[mf][nf] = __builtin_amdgcn_mfma_f32_16x16x32_bf16(qf[mf][ks], bf, sacc[mf][nf], 0, 0, 0);
      }

    // P = sigmoid(exp(s - m)/l) -> per-wave LDS tile (swizzled)
    #pragma unroll
    for (int mf = 0; mf < 2; mf++)
      #pragma unroll
      for (int nf = 0; nf < 8; nf++){
        int t = nf*16 + (l & 15);
        int c = t >> 3, tl = t & 7;
        #pragma unroll
        for (int r = 0; r < 4; r++){
          int sl = mf*16 + (l >> 4)*4 + r;
          float e = __expf(sacc[mf][nf][r]*SCALE - mrow[mf][r]);
          float p = e * linv[mf][r];
          float a = 1.f / (1.f + __expf(-p));
          Ps[w*4096 + sl*128 + ((c ^ (sl & 15))*8) + tl] = f2bf(a);
        }
      }

    // PV
    #pragma unroll
    for (int ks = 0; ks < 4; ks++){
      short8 af[2];
      #pragma unroll
      for (int mf = 0; mf < 2; mf++){
        int sl = mf*16 + (l & 15);
        int cw = (ks*4 + (l >> 4)) ^ (sl & 15);
        af[mf] = *reinterpret_cast<const short8*>(&Ps[w*4096 + sl*128 + cw*8]);
      }
      #pragma unroll
      for (int nf = 0; nf < 4; nf++){
        int row = nf*16 + (l & 15);
        int cw = (ks*4 + (l >> 4)) ^ (row & 15);
        short8 vf = *reinterpret_cast<const short8*>(&Vs[(row*16 + cw)*8]);
        #pragma unroll
        for (int mf = 0; mf < 2; mf++)
          oacc[mf][nf] = __builtin_amdgcn_mfma_f32_16x16x32_bf16(af[mf], vf, oacc[mf][nf], 0, 0, 0);
      }
    }
  }
  #pragma unroll
  for (int mf = 0; mf < 2; mf++)
    #pragma unroll
    for (int nf = 0; nf < 4; nf++)
      #pragma unroll
      for (int r = 0; r < 4; r++){
        int s_ = qt*128 + w*32 + mf*16 + (l >> 4)*4 + r;
        int d_ = nf*16 + (l & 15);
        AO[((long)bh*S + s_)*DH + d_] = f2bf(oacc[mf][nf][r]);
      }
}

// ---------------- launch ----------------
extern "C" void kernel_launch(void* const* d_in, const int* in_sizes, int n_in,
                              void* d_out, int out_size, void* d_ws, size_t ws_size,
                              hipStream_t stream)
{
  const float* query = (const float*)d_in[0];
  const float* key_  = (const float*)d_in[1];
  const float* value = (const float*)d_in[2];
  const float* Wq = (const float*)d_in[3];
  const float* bq = (const float*)d_in[4];
  const float* Wk = (const float*)d_in[5];
  const float* bk = (const float*)d_in[6];
  const float* Wv = (const float*)d_in[7];
  const float* bv = (const float*)d_in[8];
  const float* Wo = (const float*)d_in[9];
  const float* bo = (const float*)d_in[10];

  char* ws = (char*)d_ws;
  const size_t XSZ = (size_t)8192 * 512 * 2;   // 8 MiB (bf16 activation)
  const size_t WSZ = (size_t)512 * 512 * 2;    // 512 KiB (bf16 weight)
  u16* xq  = (u16*)(ws);
  u16* xk  = (u16*)(ws + XSZ);
  u16* xv  = (u16*)(ws + 2*XSZ);
  u16* wqb = (u16*)(ws + 3*XSZ);
  u16* wkb = (u16*)(ws + 3*XSZ + WSZ);
  u16* wvb = (u16*)(ws + 3*XSZ + 2*WSZ);
  u16* wob = (u16*)(ws + 3*XSZ + 3*WSZ);
  u16* Qp  = (u16*)(ws + 3*XSZ + 4*WSZ);
  u16* Kp  = (u16*)(ws + 4*XSZ + 4*WSZ);
  u16* Vtp = (u16*)(ws + 5*XSZ + 4*WSZ);
  float* mbuf = (float*)(ws + 6*XSZ + 4*WSZ);
  float* lbuf = (float*)(ws + 6*XSZ + 4*WSZ + (size_t)32*2048*4);
  u16* AO = xq;  // xq is dead after the Q projection

  const int n4x = 8192*512/4;   // 1,048,576
  const int n4w = 512*512/4;    // 65,536
  k_cvt_bf16<<<n4x/256, 256, 0, stream>>>(query, xq, n4x);
  k_cvt_bf16<<<n4x/256, 256, 0, stream>>>(key_,  xk, n4x);
  k_cvt_bf16<<<n4x/256, 256, 0, stream>>>(value, xv, n4x);
  k_cvt_bf16<<<n4w/256, 256, 0, stream>>>(Wq, wqb, n4w);
  k_cvt_bf16<<<n4w/256, 256, 0, stream>>>(Wk, wkb, n4w);
  k_cvt_bf16<<<n4w/256, 256, 0, stream>>>(Wv, wvb, n4w);
  k_cvt_bf16<<<n4w/256, 256, 0, stream>>>(Wo, wob, n4w);

  dim3 gg(64, 4), bb(256);
  k_gemm_bt<0><<<gg, bb, 0, stream>>>(xq, wqb, bq, (void*)Qp);
  k_gemm_bt<0><<<gg, bb, 0, stream>>>(xk, wkb, bk, (void*)Kp);
  k_gemm_bt<2><<<gg, bb, 0, stream>>>(xv, wvb, bv, (void*)Vtp);

  k_attn_pass1<<<dim3(16, 32), bb, 0, stream>>>(Qp, Kp, mbuf, lbuf);
  k_attn_pass2<<<dim3(16, 32), bb, 0, stream>>>(Qp, Kp, Vtp, mbuf, lbuf, AO);

  k_gemm_bt<3><<<gg, bb, 0, stream>>>(AO, wob, bo, d_out);
}

// Round 2
// 150.464 us; speedup vs baseline: 2.4601x; 2.4601x over previous
//
#include <hip/hip_runtime.h>
#include <stdint.h>
#include <math.h>

using u16    = unsigned short;
using short8 = __attribute__((ext_vector_type(8))) short;
using f32x4  = __attribute__((ext_vector_type(4))) float;

#define DEVI __device__ __forceinline__

static constexpr int S  = 2048;
static constexpr int D  = 512;
static constexpr int DH = 64;
// (1/sqrt(512)) * log2(e)  -> e^(s/sqrt(512)) = exp2(s*C2)
static constexpr float C2 = 0.063763906f;

DEVI u16 f2bf(float f){
  uint32_t u = __float_as_uint(f);
  u = u + 0x7FFFu + ((u >> 16) & 1u);   // RNE
  return (u16)(u >> 16);
}

DEVI uint32_t cvt_pk_bf16(float a, float b){
  uint32_t d;
  asm("v_cvt_pk_bf16_f32 %0, %1, %2" : "=v"(d) : "v"(a), "v"(b));
  return d;
}

// ---------------- fused fp32 -> bf16 converts ----------------
__global__ void k_cvt3(const float* __restrict__ a, const float* __restrict__ b,
                       const float* __restrict__ c, u16* __restrict__ out){
  int i = blockIdx.x * blockDim.x + threadIdx.x;   // over 3 * 2^20 float4s
  const float* src = (i < (1<<20)) ? a : (i < (2<<20) ? b : c);
  float4 v = reinterpret_cast<const float4*>(src)[i & ((1<<20)-1)];
  uint2 o;
  o.x = (uint32_t)f2bf(v.x) | ((uint32_t)f2bf(v.y) << 16);
  o.y = (uint32_t)f2bf(v.z) | ((uint32_t)f2bf(v.w) << 16);
  reinterpret_cast<uint2*>(out)[i] = o;
}

__global__ void k_cvtw(const float* __restrict__ a, const float* __restrict__ b,
                       const float* __restrict__ c, const float* __restrict__ d,
                       u16* __restrict__ out){
  int i = blockIdx.x * blockDim.x + threadIdx.x;   // over 4 * 2^16 float4s
  int sel = i >> 16;
  const float* src = sel == 0 ? a : sel == 1 ? b : sel == 2 ? c : d;
  float4 v = reinterpret_cast<const float4*>(src)[i & ((1<<16)-1)];
  uint2 o;
  o.x = (uint32_t)f2bf(v.x) | ((uint32_t)f2bf(v.y) << 16);
  o.y = (uint32_t)f2bf(v.z) | ((uint32_t)f2bf(v.w) << 16);
  reinterpret_cast<uint2*>(out)[i] = o;
}

// ---------------- GEMM: C[m][n] = sum_k A[m][k]*W[n][k] + bias ----------------
// 512 threads, 8 waves (4m x 2n), tile 128x128, BK=64.
// MODE 0: out bf16 at ((b*8+h)*2048+s)*64+d
// MODE 2: out bf16 transposed ((b*8+h)*64+d)*2048+s
// MODE 3: A head-interleaved bf16; bias is bias2[b][n]; out fp32 row-major
template<int MODE>
__global__ __launch_bounds__(512)
void k_gemm_bt(const u16* __restrict__ A, const u16* __restrict__ W,
               const float* __restrict__ bias, void* __restrict__ outp)
{
  __shared__ u16 As[128*64];
  __shared__ u16 Bs[128*64];
  const int tid = threadIdx.x;
  const int w = tid >> 6, l = tid & 63;
  const int wm = w & 3, wn = w >> 2;
  const int m0 = blockIdx.x * 128, n0 = blockIdx.y * 128;

  f32x4 acc[2][4];
  #pragma unroll
  for (int i = 0; i < 2; i++)
    #pragma unroll
    for (int j = 0; j < 4; j++) acc[i][j] = (f32x4){0.f,0.f,0.f,0.f};

  for (int kt = 0; kt < D; kt += 64){
    __syncthreads();
    #pragma unroll
    for (int j = 0; j < 2; j++){
      int idx = j*512 + tid;
      int row = idx >> 3, c = idx & 7;
      int k = kt + c*8;
      long ga;
      if constexpr (MODE == 3){
        int m = m0 + row;
        ga = ((long)(((m >> 11)*8 + (k >> 6))*2048 + (m & 2047)))*64 + (k & 63);
      } else {
        ga = (long)(m0 + row)*D + k;
      }
      *reinterpret_cast<short8*>(&As[(row*8 + (c ^ (row & 7)))*8]) =
          *reinterpret_cast<const short8*>(&A[ga]);
      *reinterpret_cast<short8*>(&Bs[(row*8 + (c ^ (row & 7)))*8]) =
          *reinterpret_cast<const short8*>(&W[(long)(n0 + row)*D + k]);
    }
    __syncthreads();
    #pragma unroll
    for (int ks = 0; ks < 2; ks++){
      short8 af[2];
      #pragma unroll
      for (int mf = 0; mf < 2; mf++){
        int row = wm*32 + mf*16 + (l & 15);
        int cw = (ks*4 + (l >> 4)) ^ (row & 7);
        af[mf] = *reinterpret_cast<const short8*>(&As[(row*8 + cw)*8]);
      }
      #pragma unroll
      for (int nf = 0; nf < 4; nf++){
        int row = wn*64 + nf*16 + (l & 15);
        int cw = (ks*4 + (l >> 4)) ^ (row & 7);
        short8 bf = *reinterpret_cast<const short8*>(&Bs[(row*8 + cw)*8]);
        #pragma unroll
        for (int mf = 0; mf < 2; mf++)
          acc[mf][nf] = __builtin_amdgcn_mfma_f32_16x16x32_bf16(af[mf], bf, acc[mf][nf], 0, 0, 0);
      }
    }
  }
  #pragma unroll
  for (int mf = 0; mf < 2; mf++){
    #pragma unroll
    for (int nf = 0; nf < 4; nf++){
      int n = n0 + wn*64 + nf*16 + (l & 15);
      float bi;
      if constexpr (MODE == 3) bi = bias[(m0 >> 11)*512 + n];
      else                     bi = bias[n];
      if constexpr (MODE == 2){
        int mb = m0 + wm*32 + mf*16 + (l >> 4)*4;
        int b_ = mb >> 11, s_ = mb & 2047;
        int h_ = n >> 6, d_ = n & 63;
        uint2 o;
        o.x = (uint32_t)f2bf(acc[mf][nf][0] + bi) | ((uint32_t)f2bf(acc[mf][nf][1] + bi) << 16);
        o.y = (uint32_t)f2bf(acc[mf][nf][2] + bi) | ((uint32_t)f2bf(acc[mf][nf][3] + bi) << 16);
        *reinterpret_cast<uint2*>(&((u16*)outp)[((long)((b_*8 + h_)*64 + d_))*2048 + s_]) = o;
      } else {
        #pragma unroll
        for (int r = 0; r < 4; r++){
          int m = m0 + wm*32 + mf*16 + (l >> 4)*4 + r;
          float v = acc[mf][nf][r] + bi;
          if constexpr (MODE == 3){
            ((float*)outp)[(long)m*D + n] = v;
          } else {
            int b_ = m >> 11, s_ = m & 2047;
            int h_ = n >> 6, d_ = n & 63;
            ((u16*)outp)[((long)((b_*8 + h_)*2048 + s_))*64 + d_] = f2bf(v);
          }
        }
      }
    }
  }
}

// ---------------- SV[bh][d] = sum_t Vt[bh][d][t] ----------------
__global__ __launch_bounds__(256)
void k_sumv(const u16* __restrict__ Vt, float* __restrict__ SV){
  const int w = threadIdx.x >> 6, l = threadIdx.x & 63;
  const int row = blockIdx.x*4 + w;     // 2048 rows = (bh,d)
  const u16* src = Vt + (long)row * S;
  float s = 0.f;
  #pragma unroll
  for (int j = 0; j < 4; j++){
    short8 v = *reinterpret_cast<const short8*>(&src[j*512 + l*8]);
    #pragma unroll
    for (int e = 0; e < 8; e++)
      s += __uint_as_float(((uint32_t)(u16)v[e]) << 16);
  }
  #pragma unroll
  for (int m = 1; m < 64; m <<= 1) s += __shfl_xor(s, m, 64);
  if (l == 0) SV[row] = s;
}

// ---------------- bias2[b][n] = bo[n] + 0.5 * sum_k SV[b][k]*Wo[n][k] ----------------
__global__ __launch_bounds__(256)
void k_bias2(const float* __restrict__ SV, const float* __restrict__ Wo,
             const float* __restrict__ bo, float* __restrict__ bias2){
  const int w = threadIdx.x >> 6, l = threadIdx.x & 63;
  const int idx = blockIdx.x*4 + w;     // 2048 = (b,n)
  const int b = idx >> 9, n = idx & 511;
  float dot = 0.f;
  #pragma unroll
  for (int j = 0; j < 2; j++){
    float4 wv = *reinterpret_cast<const float4*>(&Wo[(long)n*512 + l*8 + j*4]);
    float4 sv = *reinterpret_cast<const float4*>(&SV[b*512 + l*8 + j*4]);
    dot += wv.x*sv.x + wv.y*sv.y + wv.z*sv.z + wv.w*sv.w;
  }
  #pragma unroll
  for (int m = 1; m < 64; m <<= 1) dot += __shfl_xor(dot, m, 64);
  if (l == 0) bias2[idx] = bo[n] + 0.5f * dot;
}

// ---------------- single-pass flash: AO = 0.25 * softmax(QK^T/sqrt(512)) V ----------------
// Swapped QK^T (mfma(K,Q) -> S^T) so P rows are lane-local contiguous keys.
__global__ __launch_bounds__(256)
void k_flash(const u16* __restrict__ Qp, const u16* __restrict__ Kp,
             const u16* __restrict__ Vt, u16* __restrict__ AO)
{
  __shared__ u16 Ks[128*64];
  __shared__ u16 Vs[64*128];
  __shared__ u16 Ps[4*32*128];
  const int tid = threadIdx.x, w = tid >> 6, l = tid & 63;
  const int bh = blockIdx.x, qt = blockIdx.y;   // bh fastest -> same-bh blocks on one XCD
  const u16* Qb = Qp + (long)bh * S * DH;
  const u16* Kb = Kp + (long)bh * S * DH;
  const u16* Vb = Vt + (long)bh * DH * S;
  u16* Pw = &Ps[w*4096];

  short8 qfr[2][2];   // B-operand fragments: n = l&15 (qrow), k = ks*32+(l>>4)*8
  #pragma unroll
  for (int qf = 0; qf < 2; qf++)
    #pragma unroll
    for (int ks = 0; ks < 2; ks++){
      int row = qt*128 + w*32 + qf*16 + (l & 15);
      qfr[qf][ks] = *reinterpret_cast<const short8*>(&Qb[(long)row*DH + ks*32 + (l >> 4)*8]);
    }

  float lsum[2] = {0.f, 0.f};
  f32x4 oacc[2][4];
  #pragma unroll
  for (int i = 0; i < 2; i++)
    #pragma unroll
    for (int j = 0; j < 4; j++) oacc[i][j] = (f32x4){0.f,0.f,0.f,0.f};

  for (int kt = 0; kt < 16; kt++){
    __syncthreads();
    #pragma unroll
    for (int j = 0; j < 4; j++){
      int idx = j*256 + tid;
      int row = idx >> 3, c = idx & 7;
      *reinterpret_cast<short8*>(&Ks[(row*8 + (c ^ (row & 7)))*8]) =
          *reinterpret_cast<const short8*>(&Kb[(long)(kt*128 + row)*DH + c*8]);
    }
    #pragma unroll
    for (int j = 0; j < 4; j++){
      int idx = j*256 + tid;
      int row = idx >> 4, c = idx & 15;
      *reinterpret_cast<short8*>(&Vs[(row*16 + (c ^ (row & 15)))*8]) =
          *reinterpret_cast<const short8*>(&Vb[(long)row*S + kt*128 + c*8]);
    }
    __syncthreads();

    // S^T = K Q^T : sacc[qf][kf], lane: qrow = qf*16+(l&15), keys kf*16+(l>>4)*4+r
    f32x4 sacc[2][8];
    #pragma unroll
    for (int i = 0; i < 2; i++)
      #pragma unroll
      for (int j = 0; j < 8; j++) sacc[i][j] = (f32x4){0.f,0.f,0.f,0.f};

    #pragma unroll
    for (int ks = 0; ks < 2; ks++)
      #pragma unroll
      for (int kf = 0; kf < 8; kf++){
        int krow = kf*16 + (l & 15);
        int cw = (ks*4 + (l >> 4)) ^ (krow & 7);
        short8 af = *reinterpret_cast<const short8*>(&Ks[(krow*8 + cw)*8]);
        sacc[0][kf] = __builtin_amdgcn_mfma_f32_16x16x32_bf16(af, qfr[0][ks], sacc[0][kf], 0, 0, 0);
        sacc[1][kf] = __builtin_amdgcn_mfma_f32_16x16x32_bf16(af, qfr[1][ks], sacc[1][kf], 0, 0, 0);
      }

    // P = e^{s/sqrt(512)} -> bf16, packed b64 writes into per-wave P tile
    #pragma unroll
    for (int qf = 0; qf < 2; qf++){
      int qrow = qf*16 + (l & 15);
      int swz = (qrow & 15) << 3;      // u16-unit XOR swizzle (bits 3..6)
      #pragma unroll
      for (int kf = 0; kf < 8; kf++){
        float e0 = __builtin_amdgcn_exp2f(sacc[qf][kf][0]*C2);
        float e1 = __builtin_amdgcn_exp2f(sacc[qf][kf][1]*C2);
        float e2 = __builtin_amdgcn_exp2f(sacc[qf][kf][2]*C2);
        float e3 = __builtin_amdgcn_exp2f(sacc[qf][kf][3]*C2);
        lsum[qf] += (e0+e1) + (e2+e3);
        uint2 pk;
        pk.x = cvt_pk_bf16(e0, e1);
        pk.y = cvt_pk_bf16(e2, e3);
        int ki = kf*16 + (l >> 4)*4;
        *reinterpret_cast<uint2*>(&Pw[qrow*128 + (ki ^ swz)]) = pk;
      }
    }

    // O += P V : A-frag from Pw (contiguous b128), B-frag from Vs
    #pragma unroll
    for (int ks = 0; ks < 4; ks++){
      short8 af2[2];
      #pragma unroll
      for (int mf = 0; mf < 2; mf++){
        int qrow = mf*16 + (l & 15);
        int ki = ks*32 + (l >> 4)*8;
        af2[mf] = *reinterpret_cast<const short8*>(&Pw[qrow*128 + (ki ^ ((qrow & 15) << 3))]);
      }
      #pragma unroll
      for (int nf = 0; nf < 4; nf++){
        int drow = nf*16 + (l & 15);
        int cw = (ks*4 + (l >> 4)) ^ (drow & 15);
        short8 vf = *reinterpret_cast<const short8*>(&Vs[(drow*16 + cw)*8]);
        #pragma unroll
        for (int mf = 0; mf < 2; mf++)
          oacc[mf][nf] = __builtin_amdgcn_mfma_f32_16x16x32_bf16(af2[mf], vf, oacc[mf][nf], 0, 0, 0);
      }
    }
  }

  // row sums: combine the 4 lane-groups, then scale + write
  #pragma unroll
  for (int qf = 0; qf < 2; qf++){
    lsum[qf] += __shfl_xor(lsum[qf], 16, 64);
    lsum[qf] += __shfl_xor(lsum[qf], 32, 64);
  }
  #pragma unroll
  for (int mf = 0; mf < 2; mf++){
    float sc[4];
    #pragma unroll
    for (int r = 0; r < 4; r++)
      sc[r] = 0.25f / __shfl(lsum[mf], (l >> 4)*4 + r, 64);
    #pragma unroll
    for (int nf = 0; nf < 4; nf++)
      #pragma unroll
      for (int r = 0; r < 4; r++){
        int s_ = qt*128 + w*32 + mf*16 + (l >> 4)*4 + r;
        int d_ = nf*16 + (l & 15);
        AO[((long)bh*S + s_)*DH + d_] = f2bf(oacc[mf][nf][r] * sc[r]);
      }
  }
}

// ---------------- launch ----------------
extern "C" void kernel_launch(void* const* d_in, const int* in_sizes, int n_in,
                              void* d_out, int out_size, void* d_ws, size_t ws_size,
                              hipStream_t stream)
{
  const float* query = (const float*)d_in[0];
  const float* key_  = (const float*)d_in[1];
  const float* value = (const float*)d_in[2];
  const float* Wq = (const float*)d_in[3];
  const float* bq = (const float*)d_in[4];
  const float* Wk = (const float*)d_in[5];
  const float* bk = (const float*)d_in[6];
  const float* Wv = (const float*)d_in[7];
  const float* bv = (const float*)d_in[8];
  const float* Wo = (const float*)d_in[9];
  const float* bo = (const float*)d_in[10];

  char* ws = (char*)d_ws;
  const size_t XSZ = (size_t)8192 * 512 * 2;   // 8 MiB
  const size_t WSZ = (size_t)512 * 512 * 2;    // 512 KiB
  u16* xq  = (u16*)(ws);
  u16* xk  = (u16*)(ws + XSZ);
  u16* xv  = (u16*)(ws + 2*XSZ);
  u16* wqb = (u16*)(ws + 3*XSZ);
  u16* wkb = (u16*)(ws + 3*XSZ + WSZ);
  u16* wvb = (u16*)(ws + 3*XSZ + 2*WSZ);
  u16* wob = (u16*)(ws + 3*XSZ + 3*WSZ);
  u16* Qp  = (u16*)(ws + 3*XSZ + 4*WSZ);
  u16* Kp  = (u16*)(ws + 4*XSZ + 4*WSZ);
  u16* Vtp = (u16*)(ws + 5*XSZ + 4*WSZ);
  float* SV    = (float*)(ws + 6*XSZ + 4*WSZ);                 // 2048 f32
  float* bias2 = (float*)(ws + 6*XSZ + 4*WSZ + 8192);          // 2048 f32
  u16* AO = xq;  // xq dead after Q projection

  k_cvt3<<<(3<<20)/256, 256, 0, stream>>>(query, key_, value, xq);
  k_cvtw<<<(4<<16)/256, 256, 0, stream>>>(Wq, Wk, Wv, Wo, wqb);

  dim3 gg(64, 4), bb(512);
  k_gemm_bt<0><<<gg, bb, 0, stream>>>(xq, wqb, bq, (void*)Qp);
  k_gemm_bt<0><<<gg, bb, 0, stream>>>(xk, wkb, bk, (void*)Kp);
  k_gemm_bt<2><<<gg, bb, 0, stream>>>(xv, wvb, bv, (void*)Vtp);

  k_sumv <<<512, 256, 0, stream>>>(Vtp, SV);
  k_bias2<<<512, 256, 0, stream>>>(SV, Wo, bo, bias2);

  k_flash<<<dim3(32, 16), dim3(256), 0, stream>>>(Qp, Kp, Vtp, AO);

  k_gemm_bt<3><<<gg, bb, 0, stream>>>(AO, wob, bias2, d_out);
}

// Round 3
// 120.504 us; speedup vs baseline: 3.0717x; 1.2486x over previous
//
#include <hip/hip_runtime.h>
#include <stdint.h>
#include <math.h>

using u16    = unsigned short;
using short8 = __attribute__((ext_vector_type(8))) short;
using f32x4  = __attribute__((ext_vector_type(4))) float;
using f32x16 = __attribute__((ext_vector_type(16))) float;
using u32x4  = __attribute__((ext_vector_type(4))) uint32_t;

#define DEVI __device__ __forceinline__
#define FENCE asm volatile("" ::: "memory")
#define GPTR(p) ((const __attribute__((address_space(1))) uint32_t*)(p))
#define LPTR(p) ((__attribute__((address_space(3))) uint32_t*)(p))

static constexpr int S  = 2048;
static constexpr int D  = 512;
static constexpr int DH = 64;
// log2(e)/sqrt(512): e^(s/sqrt(512)) = exp2(s*C2)
static constexpr float C2 = 0.063763906f;

DEVI u16 f2bf(float f){
  uint32_t u = __float_as_uint(f);
  u = u + 0x7FFFu + ((u >> 16) & 1u);   // RNE
  return (u16)(u >> 16);
}

DEVI uint32_t cvt_pk_bf16(float a, float b){
  uint32_t d;
  asm("v_cvt_pk_bf16_f32 %0, %1, %2" : "=v"(d) : "v"(a), "v"(b));
  return d;
}

// ---------------- fused fp32 -> bf16 converts ----------------
__global__ void k_cvt3(const float* __restrict__ a, const float* __restrict__ b,
                       const float* __restrict__ c, u16* __restrict__ out){
  int i = blockIdx.x * blockDim.x + threadIdx.x;
  const float* src = (i < (1<<20)) ? a : (i < (2<<20) ? b : c);
  float4 v = reinterpret_cast<const float4*>(src)[i & ((1<<20)-1)];
  uint2 o;
  o.x = (uint32_t)f2bf(v.x) | ((uint32_t)f2bf(v.y) << 16);
  o.y = (uint32_t)f2bf(v.z) | ((uint32_t)f2bf(v.w) << 16);
  reinterpret_cast<uint2*>(out)[i] = o;
}

__global__ void k_cvtw(const float* __restrict__ a, const float* __restrict__ b,
                       const float* __restrict__ c, const float* __restrict__ d,
                       u16* __restrict__ out){
  int i = blockIdx.x * blockDim.x + threadIdx.x;
  int sel = i >> 16;
  const float* src = sel == 0 ? a : sel == 1 ? b : sel == 2 ? c : d;
  float4 v = reinterpret_cast<const float4*>(src)[i & ((1<<16)-1)];
  uint2 o;
  o.x = (uint32_t)f2bf(v.x) | ((uint32_t)f2bf(v.y) << 16);
  o.y = (uint32_t)f2bf(v.z) | ((uint32_t)f2bf(v.w) << 16);
  reinterpret_cast<uint2*>(out)[i] = o;
}

// ---------------- GEMM: C[m][n] = sum_k A[m][k]*W[n][k] + bias ----------------
// 512 threads = 8 waves (4m x 2n), tile 128x128, BK=64, gload_lds dbuf.
// LDS layout: tile[row][slot] = global[row][slot ^ (row&7)]  (16B slots)
template<int MODE>
__global__ __launch_bounds__(512)
void k_gemm_bt(const u16* __restrict__ A, const u16* __restrict__ W,
               const float* __restrict__ bias, void* __restrict__ outp)
{
  __shared__ u16 As[2][128*64];
  __shared__ u16 Bs[2][128*64];
  const int tid = threadIdx.x;
  const int w = tid >> 6, l = tid & 63;
  const int wm = w & 3, wn = w >> 2;
  const int m0 = blockIdx.x * 128, n0 = blockIdx.y * 128;
  const int srow = l >> 3, sslot = l & 7;

  f32x4 acc[2][4];
  #pragma unroll
  for (int i = 0; i < 2; i++)
    #pragma unroll
    for (int j = 0; j < 4; j++)
      #pragma unroll
      for (int r = 0; r < 4; r++) acc[i][j][r] = 0.f;

  auto STAGE = [&](int buf, int kt){
    #pragma unroll
    for (int i = 0; i < 2; i++){
      int r = w*16 + i*8 + srow;
      int scol = (sslot ^ (r & 7)) * 8;
      long ga;
      if constexpr (MODE == 3){
        int m = m0 + r, k = kt + scol;
        ga = ((long)(((m >> 11)*8 + (k >> 6))*2048 + (m & 2047)))*64 + (k & 63);
      } else {
        ga = (long)(m0 + r)*D + kt + scol;
      }
      __builtin_amdgcn_global_load_lds(GPTR(A + ga), LPTR(&As[buf][(w*16 + i*8)*64]), 16, 0, 0);
      long gb = (long)(n0 + r)*D + kt + scol;
      __builtin_amdgcn_global_load_lds(GPTR(W + gb), LPTR(&Bs[buf][(w*16 + i*8)*64]), 16, 0, 0);
    }
  };

  STAGE(0, 0);
  asm volatile("s_waitcnt vmcnt(0)" ::: "memory");
  __builtin_amdgcn_s_barrier();
  FENCE;

  for (int kt = 0; kt < D; kt += 64){
    int buf = (kt >> 6) & 1;
    if (kt + 64 < D) STAGE(buf ^ 1, kt + 64);
    #pragma unroll
    for (int ks = 0; ks < 2; ks++){
      short8 af[2];
      #pragma unroll
      for (int mf = 0; mf < 2; mf++){
        int row = wm*32 + mf*16 + (l & 15);
        int cw = (ks*4 + (l >> 4)) ^ (row & 7);
        af[mf] = *reinterpret_cast<const short8*>(&As[buf][(row*8 + cw)*8]);
      }
      #pragma unroll
      for (int nf = 0; nf < 4; nf++){
        int row = wn*64 + nf*16 + (l & 15);
        int cw = (ks*4 + (l >> 4)) ^ (row & 7);
        short8 bf = *reinterpret_cast<const short8*>(&Bs[buf][(row*8 + cw)*8]);
        #pragma unroll
        for (int mf = 0; mf < 2; mf++)
          acc[mf][nf] = __builtin_amdgcn_mfma_f32_16x16x32_bf16(af[mf], bf, acc[mf][nf], 0, 0, 0);
      }
    }
    asm volatile("s_waitcnt vmcnt(0)" ::: "memory");
    __builtin_amdgcn_s_barrier();
    FENCE;
  }

  #pragma unroll
  for (int mf = 0; mf < 2; mf++){
    #pragma unroll
    for (int nf = 0; nf < 4; nf++){
      int n = n0 + wn*64 + nf*16 + (l & 15);
      float bi;
      if constexpr (MODE == 3) bi = bias[(m0 >> 11)*512 + n];
      else                     bi = bias[n];
      if constexpr (MODE == 2){
        int mb = m0 + wm*32 + mf*16 + (l >> 4)*4;
        int b_ = mb >> 11, s_ = mb & 2047;
        int h_ = n >> 6, d_ = n & 63;
        uint2 o;
        o.x = (uint32_t)f2bf(acc[mf][nf][0] + bi) | ((uint32_t)f2bf(acc[mf][nf][1] + bi) << 16);
        o.y = (uint32_t)f2bf(acc[mf][nf][2] + bi) | ((uint32_t)f2bf(acc[mf][nf][3] + bi) << 16);
        *reinterpret_cast<uint2*>(&((u16*)outp)[((long)((b_*8 + h_)*64 + d_))*2048 + s_]) = o;
      } else {
        #pragma unroll
        for (int r = 0; r < 4; r++){
          int m = m0 + wm*32 + mf*16 + (l >> 4)*4 + r;
          float v = acc[mf][nf][r] + bi;
          if constexpr (MODE == 3){
            ((float*)outp)[(long)m*D + n] = v;
          } else {
            int b_ = m >> 11, s_ = m & 2047;
            int h_ = n >> 6, d_ = n & 63;
            ((u16*)outp)[((long)((b_*8 + h_)*2048 + s_))*64 + d_] = f2bf(v);
          }
        }
      }
    }
  }
}

// ---------------- SV[bh][d] = sum_t Vt[bh][d][t] ----------------
__global__ __launch_bounds__(256)
void k_sumv(const u16* __restrict__ Vt, float* __restrict__ SV){
  const int w = threadIdx.x >> 6, l = threadIdx.x & 63;
  const int row = blockIdx.x*4 + w;
  const u16* src = Vt + (long)row * S;
  float s = 0.f;
  #pragma unroll
  for (int j = 0; j < 4; j++){
    short8 v = *reinterpret_cast<const short8*>(&src[j*512 + l*8]);
    #pragma unroll
    for (int e = 0; e < 8; e++)
      s += __uint_as_float(((uint32_t)(u16)v[e]) << 16);
  }
  #pragma unroll
  for (int m = 1; m < 64; m <<= 1) s += __shfl_xor(s, m, 64);
  if (l == 0) SV[row] = s;
}

// ---------------- bias2[b][n] = bo[n] + 0.5 * sum_k SV[b][k]*Wo[n][k] ----------------
__global__ __launch_bounds__(256)
void k_bias2(const float* __restrict__ SV, const float* __restrict__ Wo,
             const float* __restrict__ bo, float* __restrict__ bias2){
  const int w = threadIdx.x >> 6, l = threadIdx.x & 63;
  const int idx = blockIdx.x*4 + w;
  const int b = idx >> 9, n = idx & 511;
  float dot = 0.f;
  #pragma unroll
  for (int j = 0; j < 2; j++){
    float4 wv = *reinterpret_cast<const float4*>(&Wo[(long)n*512 + l*8 + j*4]);
    float4 sv = *reinterpret_cast<const float4*>(&SV[b*512 + l*8 + j*4]);
    dot += wv.x*sv.x + wv.y*sv.y + wv.z*sv.z + wv.w*sv.w;
  }
  #pragma unroll
  for (int m = 1; m < 64; m <<= 1) dot += __shfl_xor(dot, m, 64);
  if (l == 0) bias2[idx] = bo[n] + 0.5f * dot;
}

// ---------------- single-pass flash, 32x32x16 MFMA, in-register P ----------------
// AO = 0.25 * softmax(QK^T/sqrt(512)) V   (per wave: 32 q-rows; KVBLK=64)
__global__ __launch_bounds__(256)
void k_flash(const u16* __restrict__ Qp, const u16* __restrict__ Kp,
             const u16* __restrict__ Vt, u16* __restrict__ AO)
{
  __shared__ u16 Ks[2][64*64];
  __shared__ u16 Vs[2][64*64];
  const int tid = threadIdx.x, w = tid >> 6, l = tid & 63;
  const int bid = blockIdx.x;
  const int bh = bid & 31, qt = bid >> 5;
  const u16* Qb = Qp + (long)bh * S * DH;
  const u16* Kb = Kp + (long)bh * S * DH;
  const u16* Vb = Vt + (long)bh * DH * S;

  const int hi = l >> 5, ln = l & 31;
  const int srow = l >> 3, sslot = l & 7;

  // Q B-frags (register-resident): lane holds Q[qrow=ln][c*16 + hi*8 .. +7]
  short8 qfr[4];
  #pragma unroll
  for (int c = 0; c < 4; c++){
    int row = qt*128 + w*32 + ln;
    qfr[c] = *reinterpret_cast<const short8*>(&Qb[(long)row*DH + c*16 + hi*8]);
  }

  auto STAGE = [&](int buf, int kt){
    #pragma unroll
    for (int i = 0; i < 2; i++){
      int r = w*16 + i*8 + srow;                 // 0..63
      int scol = (sslot ^ (r & 7)) * 8;          // inverse-swizzled source col
      __builtin_amdgcn_global_load_lds(GPTR(Kb + (long)(kt*64 + r)*DH + scol),
                                       LPTR(&Ks[buf][(w*16 + i*8)*64]), 16, 0, 0);
      __builtin_amdgcn_global_load_lds(GPTR(Vb + (long)r*S + kt*64 + scol),
                                       LPTR(&Vs[buf][(w*16 + i*8)*64]), 16, 0, 0);
    }
  };

  f32x16 oacc[2];
  #pragma unroll
  for (int j = 0; j < 2; j++)
    #pragma unroll
    for (int r = 0; r < 16; r++) oacc[j][r] = 0.f;
  float lsum = 0.f;

  STAGE(0, 0);
  asm volatile("s_waitcnt vmcnt(0)" ::: "memory");   // Q + first tile
  __builtin_amdgcn_s_barrier();
  FENCE;

  for (int kt = 0; kt < 32; kt++){
    int buf = kt & 1;
    if (kt + 1 < 32) STAGE(buf ^ 1, kt + 1);
    #pragma unroll
    for (int kf = 0; kf < 2; kf++){
      // QK^T (swapped): S^T[key][qrow]; lane: qrow=ln, 16 keys in regs
      f32x16 sacc;
      #pragma unroll
      for (int r = 0; r < 16; r++) sacc[r] = 0.f;
      #pragma unroll
      for (int c = 0; c < 4; c++){
        int key = kf*32 + ln;
        int slot = (c*2 + hi) ^ (key & 7);
        short8 kfrag = *reinterpret_cast<const short8*>(&Ks[buf][key*64 + slot*8]);
        sacc = __builtin_amdgcn_mfma_f32_32x32x16_bf16(kfrag, qfr[c], sacc, 0, 0, 0);
      }
      // exp + row-sum + pack
      float e[16];
      #pragma unroll
      for (int r = 0; r < 16; r++) e[r] = __builtin_amdgcn_exp2f(sacc[r] * C2);
      #pragma unroll
      for (int r = 0; r < 16; r += 4) lsum += (e[r] + e[r+1]) + (e[r+2] + e[r+3]);
      uint32_t pk[8];
      #pragma unroll
      for (int j = 0; j < 8; j++) pk[j] = cvt_pk_bf16(e[2*j], e[2*j+1]);
      // PV: per 16-key chain, permlane32_swap builds the A-frag in-register
      #pragma unroll
      for (int ch = 0; ch < 2; ch++){
        auto s1 = __builtin_amdgcn_permlane32_swap(pk[ch*4+0], pk[ch*4+2], false, false);
        auto s2 = __builtin_amdgcn_permlane32_swap(pk[ch*4+1], pk[ch*4+3], false, false);
        u32x4 av = { (uint32_t)s1[0], (uint32_t)s2[0], (uint32_t)s1[1], (uint32_t)s2[1] };
        short8 af = __builtin_bit_cast(short8, av);
        int k0 = kf*32 + ch*16;
        #pragma unroll
        for (int nf = 0; nf < 2; nf++){
          int d = nf*32 + ln;
          int slot = ((k0 >> 3) + hi) ^ (d & 7);
          short8 vfrag = *reinterpret_cast<const short8*>(&Vs[buf][d*64 + slot*8]);
          oacc[nf] = __builtin_amdgcn_mfma_f32_32x32x16_bf16(af, vfrag, oacc[nf], 0, 0, 0);
        }
      }
    }
    asm volatile("s_waitcnt vmcnt(0)" ::: "memory");
    __builtin_amdgcn_s_barrier();
    FENCE;
  }

  // l per qrow: halves combine; scale = 0.25/l
  lsum += __shfl_xor(lsum, 32, 64);
  float linv = 0.25f / lsum;          // valid for qrow = ln
  #pragma unroll
  for (int r = 0; r < 16; r++){
    int qrow = (r & 3) + 8*(r >> 2) + 4*hi;
    float sc = __shfl(linv, qrow, 64);
    int s_ = qt*128 + w*32 + qrow;
    #pragma unroll
    for (int nf = 0; nf < 2; nf++){
      int d_ = nf*32 + ln;
      AO[((long)bh*S + s_)*DH + d_] = f2bf(oacc[nf][r] * sc);
    }
  }
}

// ---------------- launch ----------------
extern "C" void kernel_launch(void* const* d_in, const int* in_sizes, int n_in,
                              void* d_out, int out_size, void* d_ws, size_t ws_size,
                              hipStream_t stream)
{
  const float* query = (const float*)d_in[0];
  const float* key_  = (const float*)d_in[1];
  const float* value = (const float*)d_in[2];
  const float* Wq = (const float*)d_in[3];
  const float* bq = (const float*)d_in[4];
  const float* Wk = (const float*)d_in[5];
  const float* bk = (const float*)d_in[6];
  const float* Wv = (const float*)d_in[7];
  const float* bv = (const float*)d_in[8];
  const float* Wo = (const float*)d_in[9];
  const float* bo = (const float*)d_in[10];

  char* ws = (char*)d_ws;
  const size_t XSZ = (size_t)8192 * 512 * 2;   // 8 MiB
  const size_t WSZ = (size_t)512 * 512 * 2;    // 512 KiB
  u16* xq  = (u16*)(ws);
  u16* xk  = (u16*)(ws + XSZ);
  u16* xv  = (u16*)(ws + 2*XSZ);
  u16* wqb = (u16*)(ws + 3*XSZ);
  u16* wkb = (u16*)(ws + 3*XSZ + WSZ);
  u16* wvb = (u16*)(ws + 3*XSZ + 2*WSZ);
  u16* wob = (u16*)(ws + 3*XSZ + 3*WSZ);
  u16* Qp  = (u16*)(ws + 3*XSZ + 4*WSZ);
  u16* Kp  = (u16*)(ws + 4*XSZ + 4*WSZ);
  u16* Vtp = (u16*)(ws + 5*XSZ + 4*WSZ);
  float* SV    = (float*)(ws + 6*XSZ + 4*WSZ);
  float* bias2 = (float*)(ws + 6*XSZ + 4*WSZ + 8192);
  u16* AO = xq;  // xq dead after Q projection

  k_cvt3<<<(3<<20)/256, 256, 0, stream>>>(query, key_, value, xq);
  k_cvtw<<<(4<<16)/256, 256, 0, stream>>>(Wq, Wk, Wv, Wo, wqb);

  dim3 gg(64, 4), bb(512);
  k_gemm_bt<0><<<gg, bb, 0, stream>>>(xq, wqb, bq, (void*)Qp);
  k_gemm_bt<0><<<gg, bb, 0, stream>>>(xk, wkb, bk, (void*)Kp);
  k_gemm_bt<2><<<gg, bb, 0, stream>>>(xv, wvb, bv, (void*)Vtp);

  k_sumv <<<512, 256, 0, stream>>>(Vtp, SV);
  k_bias2<<<512, 256, 0, stream>>>(SV, Wo, bo, bias2);

  k_flash<<<512, 256, 0, stream>>>(Qp, Kp, Vtp, AO);

  k_gemm_bt<3><<<gg, bb, 0, stream>>>(AO, wob, bias2, d_out);
}